// Round 2
// baseline (226.430 us; speedup 1.0000x reference)
//
#include <hip/hip_runtime.h>

// Spatial transformer: affine grid-sample, reflect padding, bilinear.
// x: (B=32, C=3, H=512, W=512) fp32; p: (B,4) fp32 = [tx, ty, theta, scale].
//
// R2: map each wave to an 8x8 output tile (block = 4 waves = 16x16 tile).
// With a 64x1 strip, one gather's 64 lanes span up to ~55 image rows ->
// up to ~55 L1 transactions per load instruction. An 8x8 tile's footprint
// is a rotated ~8ts x 8ts square (~11 rows x 1-2 lines) -> ~2-3x fewer
// L1 splits on the 12 gathers/thread.

#define B_ 32
#define C_ 3
#define H_ 512
#define W_ 512
#define TILE 16   // block tile (2x2 waves of 8x8)

__device__ __forceinline__ float reflect_coord(float coord, int size) {
    float span = (float)size;
    float c = fabsf(coord + 0.5f);
    float flips = floorf(c / span);
    float extra = c - flips * span;
    float m = fmodf(flips, 2.0f);
    c = ((m == 0.0f) ? extra : (span - extra)) - 0.5f;
    return fminf(fmaxf(c, 0.0f), (float)(size - 1));
}

__global__ __launch_bounds__(256)
void st_kernel(const float* __restrict__ x, const float* __restrict__ p,
               float* __restrict__ out) {
    const int tid  = threadIdx.x;
    const int wave = tid >> 6;        // 0..3
    const int lane = tid & 63;
    const int lx = lane & 7;          // 0..7 within wave tile
    const int ly = lane >> 3;         // 0..7
    const int wx = wave & 1;          // 2x2 wave arrangement
    const int wy = wave >> 1;

    const int col = blockIdx.x * TILE + wx * 8 + lx;
    const int row = blockIdx.y * TILE + wy * 8 + ly;
    const int b   = blockIdx.z;       // wave-uniform -> scalar param loads

    const float tx = p[b * 4 + 0];
    const float ty = p[b * 4 + 1];
    const float th = p[b * 4 + 2];
    const float ts = p[b * 4 + 3];
    const float cth = cosf(th), sth = sinf(th);
    const float a  =  ts * cth;
    const float bb = -ts * sth;
    const float d  =  ts * sth;
    const float e  =  ts * cth;

    const float xs = ((float)col + 0.5f) * (2.0f / (float)W_) - 1.0f;
    const float ys = ((float)row + 0.5f) * (2.0f / (float)H_) - 1.0f;

    const float gx = a * xs + bb * ys + tx;
    const float gy = d * xs + e  * ys + ty;

    float ix = ((gx + 1.0f) * (float)W_ - 1.0f) * 0.5f;
    float iy = ((gy + 1.0f) * (float)H_ - 1.0f) * 0.5f;
    ix = reflect_coord(ix, W_);
    iy = reflect_coord(iy, H_);

    const float ix0f = floorf(ix);
    const float iy0f = floorf(iy);
    const float fx = ix - ix0f;
    const float fy = iy - iy0f;

    const int x0 = min(max((int)ix0f,     0), W_ - 1);
    const int x1 = min(max((int)ix0f + 1, 0), W_ - 1);
    const int y0 = min(max((int)iy0f,     0), H_ - 1);
    const int y1 = min(max((int)iy0f + 1, 0), H_ - 1);

    const float w00 = (1.0f - fx) * (1.0f - fy);
    const float w01 = fx * (1.0f - fy);
    const float w10 = (1.0f - fx) * fy;
    const float w11 = fx * fy;

    const size_t plane = (size_t)H_ * W_;
    const float* img = x + (size_t)b * C_ * plane;
    float* o = out + (size_t)b * C_ * plane + (size_t)row * W_ + col;

    const size_t i00 = (size_t)y0 * W_ + x0;
    const size_t i01 = (size_t)y0 * W_ + x1;
    const size_t i10 = (size_t)y1 * W_ + x0;
    const size_t i11 = (size_t)y1 * W_ + x1;

    #pragma unroll
    for (int ch = 0; ch < C_; ++ch) {
        const float* im = img + (size_t)ch * plane;
        const float v00 = im[i00];
        const float v01 = im[i01];
        const float v10 = im[i10];
        const float v11 = im[i11];
        o[(size_t)ch * plane] = v00 * w00 + v01 * w01 + v10 * w10 + v11 * w11;
    }
}

extern "C" void kernel_launch(void* const* d_in, const int* in_sizes, int n_in,
                              void* d_out, int out_size, void* d_ws, size_t ws_size,
                              hipStream_t stream) {
    const float* x = (const float*)d_in[0];
    const float* p = (const float*)d_in[1];
    float* out = (float*)d_out;

    dim3 block(256, 1, 1);
    dim3 grid(W_ / TILE, H_ / TILE, B_);
    st_kernel<<<grid, block, 0, stream>>>(x, p, out);
}

// Round 3
// 207.636 us; speedup vs baseline: 1.0905x; 1.0905x over previous
//
#include <hip/hip_runtime.h>

// Spatial transformer: affine grid-sample, reflect padding, bilinear.
// x: (B=32, C=3, H=512, W=512) fp32; p: (B,4) fp32 = [tx, ty, theta, scale].
//
// R3: global gathers cost ~29 cyc/instruction regardless of locality (R1 vs
// R2 both ~93us). Replace them with LDS gathers: each 16x16 output tile's
// sample footprint has half-extent 7.5*ts*(|c|+|s|) <= 10.6 px; reflect+clip
// are 1-Lipschitz, so the post-reflect footprint fits a 32x32 box around the
// reflected center (margin ~1.8px after 4-aligning bx0). Stage 32x32 x 3ch
// into LDS with coalesced float4 loads, gather via ds_read_b32.

#define B_ 32
#define C_ 3
#define H_ 512
#define W_ 512
#define BOX 32
#define LSTRIDE 36                    // keeps float4 LDS writes 16B-aligned
#define CH_WORDS (BOX * LSTRIDE)      // 1152 words per channel

__device__ __forceinline__ float reflect_coord(float coord, int size) {
    float span = (float)size;
    float c = fabsf(coord + 0.5f);
    float flips = floorf(c / span);
    float extra = c - flips * span;
    float m = fmodf(flips, 2.0f);
    c = ((m == 0.0f) ? extra : (span - extra)) - 0.5f;
    return fminf(fmaxf(c, 0.0f), (float)(size - 1));
}

__global__ __launch_bounds__(256)
void st_kernel(const float* __restrict__ x, const float* __restrict__ p,
               float* __restrict__ out) {
    __shared__ float smem[C_ * CH_WORDS];   // 13824 B

    const int tid = threadIdx.x;
    const int b   = blockIdx.z;             // wave-uniform -> scalar param loads

    const float tx = p[b * 4 + 0];
    const float ty = p[b * 4 + 1];
    const float th = p[b * 4 + 2];
    const float ts = p[b * 4 + 3];
    const float cth = cosf(th), sth = sinf(th);
    const float a  =  ts * cth;
    const float bb = -ts * sth;
    const float d  =  ts * sth;
    const float e  =  ts * cth;

    // ---- block-uniform staging box ----
    const float xs_c = ((float)(blockIdx.x * 16) + 8.0f) * (2.0f / W_) - 1.0f;
    const float ys_c = ((float)(blockIdx.y * 16) + 8.0f) * (2.0f / H_) - 1.0f;
    const float gxc = a * xs_c + bb * ys_c + tx;
    const float gyc = d * xs_c + e  * ys_c + ty;
    const float rcx = reflect_coord(((gxc + 1.0f) * W_ - 1.0f) * 0.5f, W_);
    const float rcy = reflect_coord(((gyc + 1.0f) * H_ - 1.0f) * 0.5f, H_);
    const float ext = 8.0f * (fabsf(a) + fabsf(bb)) + 3.0f;  // >= 7.5*ts*(|c|+|s|)+margin
    int bx0 = (int)floorf(rcx - ext);
    bx0 = (min(max(bx0, 0), W_ - BOX)) & ~3;   // 16B-aligned float4 staging
    int by0 = (int)floorf(rcy - ext);
    by0 = min(max(by0, 0), H_ - BOX);

    const size_t plane = (size_t)H_ * W_;
    const float* img = x + (size_t)b * C_ * plane;

    // ---- stage 32x32 x 3ch into LDS, coalesced float4 ----
    {
        const int srow = tid >> 3;            // 0..31
        const int scol = (tid & 7) << 2;      // 0,4,...,28
        const float* g0 = img + (size_t)(by0 + srow) * W_ + (bx0 + scol);
        const int l = srow * LSTRIDE + scol;
        #pragma unroll
        for (int ch = 0; ch < C_; ++ch) {
            const float4 v = *reinterpret_cast<const float4*>(g0 + (size_t)ch * plane);
            *reinterpret_cast<float4*>(&smem[ch * CH_WORDS + l]) = v;
        }
    }
    __syncthreads();

    // ---- per-pixel sample ----
    const int col = blockIdx.x * 16 + (tid & 15);
    const int row = blockIdx.y * 16 + (tid >> 4);

    const float xs = ((float)col + 0.5f) * (2.0f / W_) - 1.0f;
    const float ys = ((float)row + 0.5f) * (2.0f / H_) - 1.0f;
    float ix = ((a * xs + bb * ys + tx + 1.0f) * W_ - 1.0f) * 0.5f;
    float iy = ((d * xs + e  * ys + ty + 1.0f) * H_ - 1.0f) * 0.5f;
    ix = reflect_coord(ix, W_);
    iy = reflect_coord(iy, H_);

    const float ix0f = floorf(ix);
    const float iy0f = floorf(iy);
    const float fx = ix - ix0f;
    const float fy = iy - iy0f;

    const int x0 = min(max((int)ix0f,     0), W_ - 1);
    const int x1 = min(max((int)ix0f + 1, 0), W_ - 1);
    const int y0 = min(max((int)iy0f,     0), H_ - 1);
    const int y1 = min(max((int)iy0f + 1, 0), H_ - 1);

    const float w00 = (1.0f - fx) * (1.0f - fy);
    const float w01 = fx * (1.0f - fy);
    const float w10 = (1.0f - fx) * fy;
    const float w11 = fx * fy;

    const int i00 = (y0 - by0) * LSTRIDE + (x0 - bx0);
    const int i01 = (y0 - by0) * LSTRIDE + (x1 - bx0);
    const int i10 = (y1 - by0) * LSTRIDE + (x0 - bx0);
    const int i11 = (y1 - by0) * LSTRIDE + (x1 - bx0);

    float* o = out + (size_t)b * C_ * plane + (size_t)row * W_ + col;
    #pragma unroll
    for (int ch = 0; ch < C_; ++ch) {
        const float* s = &smem[ch * CH_WORDS];
        o[(size_t)ch * plane] =
            s[i00] * w00 + s[i01] * w01 + s[i10] * w10 + s[i11] * w11;
    }
}

extern "C" void kernel_launch(void* const* d_in, const int* in_sizes, int n_in,
                              void* d_out, int out_size, void* d_ws, size_t ws_size,
                              hipStream_t stream) {
    const float* x = (const float*)d_in[0];
    const float* p = (const float*)d_in[1];
    float* out = (float*)d_out;

    dim3 block(256, 1, 1);
    dim3 grid(W_ / 16, H_ / 16, B_);
    st_kernel<<<grid, block, 0, stream>>>(x, p, out);
}